// Round 1
// baseline (854.302 us; speedup 1.0000x reference)
//
#include <hip/hip_runtime.h>
#include <hip/hip_bf16.h>

namespace {

constexpr int Bc = 2, Hc = 16, Sc = 2048, Dc = 64;
constexpr float kScale = 0.125f;   // 1/sqrt(64), exact power of two
constexpr int KC = 64;             // keys staged per chunk

typedef __attribute__((ext_vector_type(8))) short bf16x8;
typedef __attribute__((ext_vector_type(4))) float f32x4;

__device__ inline short f2bf(float x) {
    // round-to-nearest-even fp32 -> bf16 (finite inputs only)
    union { float f; unsigned int u; } v;
    v.f = x;
    unsigned int r = v.u + 0x7fffu + ((v.u >> 16) & 1u);
    return (short)(r >> 16);
}

__global__ __launch_bounds__(256, 2)
void fa_fwd(const float* __restrict__ qg, const float* __restrict__ kg,
            const float* __restrict__ vg, float* __restrict__ outg,
            float* __restrict__ attng) {
    const int tid  = (int)threadIdx.x;
    const int wave = tid >> 6;
    const int lane = tid & 63;
    const int m16  = lane & 15;   // A/B-frag row/col within 16
    const int q4   = lane >> 4;   // lane quad

    const int bh = (int)blockIdx.y;
    const int qw = (int)blockIdx.x * 64 + wave * 16;  // this wave's first q row

    // K/V staged as bf16; stride 72 keeps 16B alignment for ds_read_b128
    __shared__ __align__(16) short s_k[KC][72];
    __shared__ __align__(16) short s_v[KC][72];
    // per-wave C-layout -> A-layout transpose buffer for P (stride 65: 2-way reads)
    __shared__ __align__(16) float s_p[4][16][KC + 1];

    const size_t hoff = (size_t)bh * Sc * Dc;
    const float* qh = qg + hoff;
    const float* kh = kg + hoff;
    const float* vh = vg + hoff;
    float* oh = outg + hoff;
    float* ph = attng + (size_t)bh * Sc * Sc;

    // A fragments of Q (pre-scaled; lane holds A[m16][q4*8+j]), two K-halves
    bf16x8 a0, a1;
    {
        const float* qr = qh + (size_t)(qw + m16) * Dc + q4 * 8;
        #pragma unroll
        for (int j = 0; j < 8; ++j) {
            a0[j] = f2bf(qr[j] * kScale);
            a1[j] = f2bf(qr[j + 32] * kScale);
        }
    }

    // per-lane softmax state for rows qw + q4*4 + r
    float m_i[4], l_i[4];
    #pragma unroll
    for (int r = 0; r < 4; ++r) { m_i[r] = -1e30f; l_i[r] = 0.0f; }

    // ---------------- pass 1: softmax stats (m, l) ----------------
    for (int k0 = 0; k0 < Sc; k0 += KC) {
        #pragma unroll
        for (int it = 0; it < KC * Dc / (4 * 256); ++it) {   // 4 float4 per thread
            int fid = tid + it * 256;
            int row = fid >> 4;
            int c4  = (fid & 15) * 4;
            const float4 t = *(const float4*)(kh + (size_t)(k0 + row) * Dc + c4);
            s_k[row][c4 + 0] = f2bf(t.x);
            s_k[row][c4 + 1] = f2bf(t.y);
            s_k[row][c4 + 2] = f2bf(t.z);
            s_k[row][c4 + 3] = f2bf(t.w);
        }
        __syncthreads();

        float sc[KC / 16][4];
        #pragma unroll
        for (int kt = 0; kt < KC / 16; ++kt) {
            // B-frag: lane holds K[kt*16 + m16][q4*8+j] (= B[k][n] with n=key)
            bf16x8 b0 = *(const bf16x8*)&s_k[kt * 16 + m16][q4 * 8];
            bf16x8 b1 = *(const bf16x8*)&s_k[kt * 16 + m16][q4 * 8 + 32];
            f32x4 c = {0.f, 0.f, 0.f, 0.f};
            c = __builtin_amdgcn_mfma_f32_16x16x32_bf16(a0, b0, c, 0, 0, 0);
            c = __builtin_amdgcn_mfma_f32_16x16x32_bf16(a1, b1, c, 0, 0, 0);
            #pragma unroll
            for (int r = 0; r < 4; ++r) sc[kt][r] = c[r];
        }

        // row-max across this chunk (reduce over the 16 key-lanes)
        float tmax[4];
        #pragma unroll
        for (int r = 0; r < 4; ++r) {
            tmax[r] = sc[0][r];
            #pragma unroll
            for (int kt = 1; kt < KC / 16; ++kt) tmax[r] = fmaxf(tmax[r], sc[kt][r]);
        }
        #pragma unroll
        for (int off = 8; off; off >>= 1) {
            #pragma unroll
            for (int r = 0; r < 4; ++r)
                tmax[r] = fmaxf(tmax[r], __shfl_xor(tmax[r], off));
        }

        float mn[4], tsum[4];
        #pragma unroll
        for (int r = 0; r < 4; ++r) {
            mn[r] = fmaxf(m_i[r], tmax[r]);
            float s = 0.f;
            #pragma unroll
            for (int kt = 0; kt < KC / 16; ++kt) s += __expf(sc[kt][r] - mn[r]);
            tsum[r] = s;
        }
        #pragma unroll
        for (int off = 8; off; off >>= 1) {
            #pragma unroll
            for (int r = 0; r < 4; ++r)
                tsum[r] += __shfl_xor(tsum[r], off);
        }
        #pragma unroll
        for (int r = 0; r < 4; ++r) {
            l_i[r] = l_i[r] * __expf(m_i[r] - mn[r]) + tsum[r];
            m_i[r] = mn[r];
        }
        __syncthreads();
    }

    float inv_l[4];
    #pragma unroll
    for (int r = 0; r < 4; ++r) inv_l[r] = 1.0f / l_i[r];

    // ---------------- pass 2: P write + O = P.V ----------------
    f32x4 o[4];
    #pragma unroll
    for (int dt = 0; dt < 4; ++dt) o[dt] = (f32x4){0.f, 0.f, 0.f, 0.f};

    for (int k0 = 0; k0 < Sc; k0 += KC) {
        #pragma unroll
        for (int it = 0; it < KC * Dc / (4 * 256); ++it) {
            int fid = tid + it * 256;
            int row = fid >> 4;
            int c4  = (fid & 15) * 4;
            const float4 t  = *(const float4*)(kh + (size_t)(k0 + row) * Dc + c4);
            const float4 tv = *(const float4*)(vh + (size_t)(k0 + row) * Dc + c4);
            s_k[row][c4 + 0] = f2bf(t.x);
            s_k[row][c4 + 1] = f2bf(t.y);
            s_k[row][c4 + 2] = f2bf(t.z);
            s_k[row][c4 + 3] = f2bf(t.w);
            s_v[row][c4 + 0] = f2bf(tv.x);
            s_v[row][c4 + 1] = f2bf(tv.y);
            s_v[row][c4 + 2] = f2bf(tv.z);
            s_v[row][c4 + 3] = f2bf(tv.w);
        }
        __syncthreads();

        // recompute scores, normalize, emit P (global + per-wave LDS)
        #pragma unroll
        for (int kt = 0; kt < KC / 16; ++kt) {
            bf16x8 b0 = *(const bf16x8*)&s_k[kt * 16 + m16][q4 * 8];
            bf16x8 b1 = *(const bf16x8*)&s_k[kt * 16 + m16][q4 * 8 + 32];
            f32x4 c = {0.f, 0.f, 0.f, 0.f};
            c = __builtin_amdgcn_mfma_f32_16x16x32_bf16(a0, b0, c, 0, 0, 0);
            c = __builtin_amdgcn_mfma_f32_16x16x32_bf16(a1, b1, c, 0, 0, 0);
            #pragma unroll
            for (int r = 0; r < 4; ++r) {
                float p = __expf(c[r] - m_i[r]) * inv_l[r];
                ph[(size_t)(qw + q4 * 4 + r) * Sc + (k0 + kt * 16 + m16)] = p;
                s_p[wave][q4 * 4 + r][kt * 16 + m16] = p;
            }
        }

        // O += P.V over this chunk (A from s_p, B from s_v)
        #pragma unroll
        for (int kh2 = 0; kh2 < KC / 32; ++kh2) {
            bf16x8 pa;
            #pragma unroll
            for (int j = 0; j < 8; ++j)
                pa[j] = f2bf(s_p[wave][m16][kh2 * 32 + q4 * 8 + j]);
            #pragma unroll
            for (int dt = 0; dt < 4; ++dt) {
                bf16x8 vb;
                #pragma unroll
                for (int j = 0; j < 8; ++j)
                    vb[j] = s_v[kh2 * 32 + q4 * 8 + j][dt * 16 + m16];
                o[dt] = __builtin_amdgcn_mfma_f32_16x16x32_bf16(pa, vb, o[dt], 0, 0, 0);
            }
        }
        __syncthreads();
    }

    // epilogue: O rows already normalized (used p, not e)
    #pragma unroll
    for (int dt = 0; dt < 4; ++dt) {
        #pragma unroll
        for (int r = 0; r < 4; ++r)
            oh[(size_t)(qw + q4 * 4 + r) * Dc + (dt * 16 + m16)] = o[dt][r];
    }
}

} // namespace

extern "C" void kernel_launch(void* const* d_in, const int* in_sizes, int n_in,
                              void* d_out, int out_size, void* d_ws, size_t ws_size,
                              hipStream_t stream) {
    const float* q = (const float*)d_in[0];
    const float* k = (const float*)d_in[1];
    const float* v = (const float*)d_in[2];
    float* out  = (float*)d_out;
    float* attn = out + (size_t)Bc * Hc * Sc * Dc;  // outputs concatenated: out, attn_weights
    dim3 grid(Sc / 64, Bc * Hc);
    fa_fwd<<<grid, 256, 0, stream>>>(q, k, v, out, attn);
}